// Round 1
// baseline (509.275 us; speedup 1.0000x reference)
//
#include <hip/hip_runtime.h>
#include <math.h>

#define NN 20000
#define NE 320000
#define NF (NN*64)
#define TB 16

// ---------------- weight transpose (unchanged math) ----------------
__global__ __launch_bounds__(256) void k_transpose_res(
    const float* __restrict__ Ws, const float* __restrict__ Wv,
    float* __restrict__ Wst, float* __restrict__ Wvt)
{
  int i = blockIdx.x*256 + threadIdx.x;   // 0..40959
  int spec = i >> 12;
  int g = (i >> 6) & 63;
  int f = i & 63;
  Wst[spec*4096 + f*64 + g] = Ws[i];
  Wvt[spec*4096 + f*64 + g] = Wv[i];
}

// ---------------- counting sort of edges by receiver ----------------
__global__ __launch_bounds__(256) void k_hist(const int* __restrict__ receivers,
                                              int* __restrict__ count)
{
  int e = blockIdx.x*256 + threadIdx.x;
  atomicAdd(&count[receivers[e]], 1);
}

__global__ __launch_bounds__(256) void k_scan(const int* __restrict__ count,
                                              int* __restrict__ offset)
{
  __shared__ int part[256];
  int t = threadIdx.x;
  const int PER = 79;                     // 256*79 = 20224 >= NN
  int s = 0;
  for(int i=0;i<PER;++i){ int idx = t*PER+i; if(idx < NN) s += count[idx]; }
  part[t] = s;
  __syncthreads();
  for(int off=1; off<256; off<<=1){
    int v = (t>=off) ? part[t-off] : 0;
    __syncthreads();
    part[t] += v;
    __syncthreads();
  }
  int run = t ? part[t-1] : 0;
  for(int i=0;i<PER;++i){
    int idx = t*PER+i;
    if(idx < NN){ offset[idx] = run; run += count[idx]; }
  }
  if(t==255) offset[NN] = run;
}

__global__ __launch_bounds__(256) void k_scatter(
    const int* __restrict__ receivers, const int* __restrict__ offset,
    int* __restrict__ count, int* __restrict__ order)
{
  int e = blockIdx.x*256 + threadIdx.x;
  int r = receivers[e];
  int old = atomicSub(&count[r], 1);      // countdown gives unique slot
  order[offset[r] + old - 1] = e;
}

// ---------------- node pre-pass: 4 nodes per wave ----------------
// h layout: h[n*256 + c*64 + lane], c in {s, vx, vy, vz}
__global__ __launch_bounds__(256) void k_node_pre(
    const float* __restrict__ node_feats, const float* __restrict__ W_in_s,
    const float* __restrict__ W_in_v, float* __restrict__ h)
{
  __shared__ float sh[16][4][64];
  int wave = threadIdx.x >> 6, lane = threadIdx.x & 63;
  int nb = blockIdx.x*16 + wave*4;
  #pragma unroll
  for(int k=0;k<4;++k){
    int nd = wave*4 + k;
    float4 nf = *(const float4*)(node_feats + (size_t)((nb+k)*64 + lane)*4);
    sh[nd][0][lane]=nf.x; sh[nd][1][lane]=nf.y; sh[nd][2][lane]=nf.z; sh[nd][3][lane]=nf.w;
  }
  __syncthreads();
  float as[4]={0,0,0,0}, a0[4]={0,0,0,0}, a1[4]={0,0,0,0}, a2[4]={0,0,0,0};
  for(int f=0; f<64; ++f){
    float ws = W_in_s[f*64+lane], wv = W_in_v[f*64+lane];
    #pragma unroll
    for(int k=0;k<4;++k){
      int nd = wave*4 + k;
      as[k] = fmaf(sh[nd][0][f], ws, as[k]);
      a0[k] = fmaf(sh[nd][1][f], wv, a0[k]);
      a1[k] = fmaf(sh[nd][2][f], wv, a1[k]);
      a2[k] = fmaf(sh[nd][3][f], wv, a2[k]);
    }
  }
  #pragma unroll
  for(int k=0;k<4;++k){
    size_t o = (size_t)(nb+k)*256 + lane;
    h[o]     = as[k]*0.125f;
    h[o+64]  = a0[k]*0.125f;
    h[o+128] = a1[k]*0.125f;
    h[o+192] = a2[k]*0.125f;
  }
}

// ---------------- edge kernel over receiver-sorted order ----------------
__global__ __launch_bounds__(256) void k_edge(
    const float* __restrict__ vectors, const float* __restrict__ radial,
    const int* __restrict__ senders, const int* __restrict__ receivers,
    const float* __restrict__ mlp_w1, const float* __restrict__ mlp_w2,
    const float* __restrict__ h, const int* __restrict__ order,
    float* __restrict__ agg)
{
  __shared__ int   eidS[4][TB];
  __shared__ int   sndS[4][TB];
  __shared__ int   rcvS[4][TB];
  __shared__ float vecS[4][3*TB];
  __shared__ float rad[4][8*TB];
  __shared__ float hid[4][TB][64];
  int wave = threadIdx.x >> 6, lane = threadIdx.x & 63;
  int e0 = (blockIdx.x*4 + wave)*TB;

  if(lane < TB){
    int e = order[e0 + lane];
    eidS[wave][lane] = e;
    sndS[wave][lane] = senders[e];
    rcvS[wave][lane] = receivers[e];
  }
  float wl[8];
  #pragma unroll
  for(int r=0;r<8;++r) wl[r] = mlp_w1[r*64+lane];
  __syncthreads();
  if(lane < 3*TB) vecS[wave][lane] = vectors[(size_t)eidS[wave][lane/3]*3 + lane%3];
  rad[wave][lane]    = radial[(size_t)eidS[wave][lane>>3]*8     + (lane&7)];
  rad[wave][64+lane] = radial[(size_t)eidS[wave][8+(lane>>3)]*8 + (lane&7)];
  __syncthreads();
  // hidden = silu(rad @ w1), lane = hidden unit
  #pragma unroll
  for(int t=0;t<TB;++t){
    float acc = 0.f;
    #pragma unroll
    for(int r=0;r<8;++r) acc = fmaf(rad[wave][t*8+r], wl[r], acc);
    hid[wave][t][lane] = acc / (1.f + __expf(-acc));
  }
  __syncthreads();
  // w[j][t] = hidden[t] @ w2[:, j*64+lane]
  float w[5][TB];
  #pragma unroll
  for(int j=0;j<5;++j)
    #pragma unroll
    for(int t=0;t<TB;++t) w[j][t] = 0.f;
  for(int hh=0; hh<64; hh+=2){
    float b0[5], b1[5];
    #pragma unroll
    for(int j=0;j<5;++j){
      b0[j] = mlp_w2[hh*320     + j*64 + lane];
      b1[j] = mlp_w2[(hh+1)*320 + j*64 + lane];
    }
    #pragma unroll
    for(int t=0;t<TB;++t){
      float2 hb = *(const float2*)&hid[wave][t][hh];
      #pragma unroll
      for(int j=0;j<5;++j) w[j][t] = fmaf(hb.x, b0[j], fmaf(hb.y, b1[j], w[j][t]));
    }
  }
  // messages: register-accumulate per receiver-run, flush on change (wave-uniform branch)
  float as_=0.f, av0=0.f, av1=0.f, av2=0.f;
  int cur = rcvS[wave][0];
  #pragma unroll
  for(int t=0;t<TB;++t){
    int rcv = rcvS[wave][t];
    if(rcv != cur){
      size_t ro = (size_t)cur*256 + lane;
      atomicAdd(&agg[ro],     as_);
      atomicAdd(&agg[ro+64],  av0);
      atomicAdd(&agg[ro+128], av1);
      atomicAdd(&agg[ro+192], av2);
      as_=0.f; av0=0.f; av1=0.f; av2=0.f;
      cur = rcv;
    }
    int snd = sndS[wave][t];
    float vx=vecS[wave][t*3], vy=vecS[wave][t*3+1], vz=vecS[wave][t*3+2];
    float rinv = rsqrtf(vx*vx + vy*vy + vz*vz + 1e-12f);
    float y0=vx*rinv, y1=vy*rinv, y2=vz*rinv;
    size_t so = (size_t)snd*256 + lane;
    float ss  = h[so];
    float sv0 = h[so+64], sv1 = h[so+128], sv2 = h[so+192];
    float dot = sv0*y0 + sv1*y1 + sv2*y2;
    as_ += w[0][t]*ss + w[1][t]*dot;
    float w2s = w[2][t]*ss, w3t = w[3][t], w4t = w[4][t];
    av0 += w2s*y0 + w3t*sv0 + w4t*(sv1*y2 - sv2*y1);
    av1 += w2s*y1 + w3t*sv1 + w4t*(sv2*y0 - sv0*y2);
    av2 += w2s*y2 + w3t*sv2 + w4t*(sv0*y1 - sv1*y0);
  }
  size_t ro = (size_t)cur*256 + lane;
  atomicAdd(&agg[ro],     as_);
  atomicAdd(&agg[ro+64],  av0);
  atomicAdd(&agg[ro+128], av1);
  atomicAdd(&agg[ro+192], av2);
}

// ---------------- node post-pass: 4 nodes per wave ----------------
__global__ __launch_bounds__(256) void k_node_post(
  const float* __restrict__ node_feats, const int* __restrict__ specie,
  const float* __restrict__ agg,
  const float* __restrict__ Wrst, const float* __restrict__ Wrvt,
  const float* __restrict__ W_out_s, const float* __restrict__ W_out_v,
  const float* __restrict__ W_prod_s, const float* __restrict__ W_prod_v,
  const float* __restrict__ W_lin_s, const float* __restrict__ W_lin_v,
  const float* __restrict__ W_read, float* __restrict__ out_node,
  float* __restrict__ out_feats)
{
  __shared__ float shA[16][4][64];
  __shared__ float shS[16][4][64];   // node_feats first, reused for p_s/p_v
  int wave = threadIdx.x >> 6, lane = threadIdx.x & 63;
  int nb = blockIdx.x*16 + wave*4;
  #pragma unroll
  for(int k=0;k<4;++k){
    int nd = wave*4 + k;
    size_t o = (size_t)(nb+k)*256 + lane;
    shA[nd][0][lane] = agg[o]     * (1.f/16.f);
    shA[nd][1][lane] = agg[o+64]  * (1.f/16.f);
    shA[nd][2][lane] = agg[o+128] * (1.f/16.f);
    shA[nd][3][lane] = agg[o+192] * (1.f/16.f);
    float4 nf = *(const float4*)(node_feats + (size_t)((nb+k)*64 + lane)*4);
    shS[nd][0][lane]=nf.x; shS[nd][1][lane]=nf.y; shS[nd][2][lane]=nf.z; shS[nd][3][lane]=nf.w;
  }
  int spec[4];
  #pragma unroll
  for(int k=0;k<4;++k) spec[k] = specie[nb+k];
  __syncthreads();
  float a_s[4]={0,0,0,0}, a0[4]={0,0,0,0}, a1[4]={0,0,0,0}, a2[4]={0,0,0,0};
  float r_s[4]={0,0,0,0}, r0[4]={0,0,0,0}, r1[4]={0,0,0,0}, r2[4]={0,0,0,0};
  for(int f=0; f<64; ++f){
    float wos = W_out_s[f*64+lane], wov = W_out_v[f*64+lane];
    #pragma unroll
    for(int k=0;k<4;++k){
      int nd = wave*4 + k;
      a_s[k] = fmaf(shA[nd][0][f], wos, a_s[k]);
      a0[k]  = fmaf(shA[nd][1][f], wov, a0[k]);
      a1[k]  = fmaf(shA[nd][2][f], wov, a1[k]);
      a2[k]  = fmaf(shA[nd][3][f], wov, a2[k]);
    }
    #pragma unroll
    for(int k=0;k<4;++k){
      int nd = wave*4 + k;
      float wrs = Wrst[spec[k]*4096 + f*64 + lane];
      float wrv = Wrvt[spec[k]*4096 + f*64 + lane];
      r_s[k] = fmaf(shS[nd][0][f], wrs, r_s[k]);
      r0[k]  = fmaf(shS[nd][1][f], wrv, r0[k]);
      r1[k]  = fmaf(shS[nd][2][f], wrv, r1[k]);
      r2[k]  = fmaf(shS[nd][3][f], wrv, r2[k]);
    }
  }
  __syncthreads();
  #pragma unroll
  for(int k=0;k<4;++k){
    int nd = wave*4 + k;
    float A_s = a_s[k]*0.125f, A0 = a0[k]*0.125f, A1 = a1[k]*0.125f, A2 = a2[k]*0.125f;
    float vv = A0*A0 + A1*A1 + A2*A2;
    float as2 = A_s*A_s;
    const float* Wp = W_prod_s + spec[k]*320;
    float p_s = Wp[lane]*A_s + Wp[64+lane]*as2 + Wp[128+lane]*as2*A_s
              + Wp[192+lane]*vv + Wp[256+lane]*A_s*vv;
    const float* Wq = W_prod_v + spec[k]*256;
    float coef = Wq[lane] + Wq[64+lane]*A_s + Wq[128+lane]*as2 + Wq[192+lane]*vv;
    shS[nd][0][lane] = p_s;
    shS[nd][1][lane] = coef*A0;
    shS[nd][2][lane] = coef*A1;
    shS[nd][3][lane] = coef*A2;
  }
  __syncthreads();
  float lfs[4]={0,0,0,0}, lf0[4]={0,0,0,0}, lf1[4]={0,0,0,0}, lf2[4]={0,0,0,0};
  for(int f=0; f<64; ++f){
    float wls = W_lin_s[f*64+lane], wlv = W_lin_v[f*64+lane];
    #pragma unroll
    for(int k=0;k<4;++k){
      int nd = wave*4 + k;
      lfs[k] = fmaf(shS[nd][0][f], wls, lfs[k]);
      lf0[k] = fmaf(shS[nd][1][f], wlv, lf0[k]);
      lf1[k] = fmaf(shS[nd][2][f], wlv, lf1[k]);
      lf2[k] = fmaf(shS[nd][3][f], wlv, lf2[k]);
    }
  }
  float wr = W_read[lane];
  #pragma unroll
  for(int k=0;k<4;++k){
    int n = nb + k;
    float FS = lfs[k]*0.125f + r_s[k]*0.125f;
    float F0 = lf0[k]*0.125f + r0[k]*0.125f;
    float F1 = lf1[k]*0.125f + r1[k]*0.125f;
    float F2 = lf2[k]*0.125f + r2[k]*0.125f;
    float x = FS * wr;
    #pragma unroll
    for(int off=32; off; off>>=1) x += __shfl_down(x, off);
    if(lane==0) out_node[n] = x*0.125f;
    float4 o4; o4.x=FS; o4.y=F0; o4.z=F1; o4.w=F2;
    *(float4*)(out_feats + (size_t)(n*64+lane)*4) = o4;
  }
}

extern "C" void kernel_launch(void* const* d_in, const int* in_sizes, int n_in,
                              void* d_out, int out_size, void* d_ws, size_t ws_size,
                              hipStream_t stream) {
  const float* vectors    = (const float*)d_in[0];
  const float* node_feats = (const float*)d_in[1];
  const int*   node_specie= (const int*)  d_in[2];
  const float* radial     = (const float*)d_in[3];
  const int*   senders    = (const int*)  d_in[4];
  const int*   receivers  = (const int*)  d_in[5];
  const float* W_res_s    = (const float*)d_in[6];
  const float* W_res_v    = (const float*)d_in[7];
  const float* W_in_s     = (const float*)d_in[8];
  const float* W_in_v     = (const float*)d_in[9];
  const float* mlp_w1     = (const float*)d_in[10];
  const float* mlp_w2     = (const float*)d_in[11];
  const float* W_out_s    = (const float*)d_in[12];
  const float* W_out_v    = (const float*)d_in[13];
  const float* W_prod_s   = (const float*)d_in[14];
  const float* W_prod_v   = (const float*)d_in[15];
  const float* W_lin_s    = (const float*)d_in[16];
  const float* W_lin_v    = (const float*)d_in[17];
  const float* W_read     = (const float*)d_in[18];

  float* ws   = (float*)d_ws;
  float* h    = ws;                          // 4*NF, [node][4][64]
  float* agg  = ws + 4*(size_t)NF;           // 4*NF, [node][4][64]
  float* Wrst = ws + 8*(size_t)NF;           // 40960
  float* Wrvt = Wrst + 40960;                // 40960
  int*   order  = (int*)(Wrvt + 40960);      // NE
  int*   offset = order + NE;                // NN+1
  int*   count  = offset + NN + 1;           // NN

  hipMemsetAsync(agg,   0, (size_t)4*NF*sizeof(float), stream);
  hipMemsetAsync(count, 0, (size_t)NN*sizeof(int), stream);
  k_transpose_res<<<160, 256, 0, stream>>>(W_res_s, W_res_v, Wrst, Wrvt);
  k_hist   <<<NE/256, 256, 0, stream>>>(receivers, count);
  k_scan   <<<1,      256, 0, stream>>>(count, offset);
  k_scatter<<<NE/256, 256, 0, stream>>>(receivers, offset, count, order);
  k_node_pre<<<NN/16, 256, 0, stream>>>(node_feats, W_in_s, W_in_v, h);
  k_edge<<<NE/(4*TB), 256, 0, stream>>>(vectors, radial, senders, receivers,
                                        mlp_w1, mlp_w2, h, order, agg);
  k_node_post<<<NN/16, 256, 0, stream>>>(node_feats, node_specie, agg,
                                         Wrst, Wrvt, W_out_s, W_out_v,
                                         W_prod_s, W_prod_v, W_lin_s, W_lin_v,
                                         W_read, (float*)d_out, (float*)d_out + NN);
}